// Round 3
// baseline (66.280 us; speedup 1.0000x reference)
//
#include <hip/hip_runtime.h>

// GANLoss gather-reduce, fused single kernel:
//   out = -(1/(N*F)) * sum_{n,f} prob_flat[n, OFF[f]+target[n,f]] * reward[n]
// N = 65536, C = 3200, F = 6.  target is int32 (harness convention).
// One thread per (n,f) element -> 1536 blocks x 256 threads (24 waves/CU).
// Deterministic: fixed-order shuffle/LDS reduces; last block (atomic counter)
// sums the 1536 block partials in a fixed order.

#define NROWS   65536
#define NCOLS   3200
#define NFLD    6
#define NTOT    (NROWS * NFLD)      // 393216
#define BLK     256
#define NBLOCKS (NTOT / BLK)        // 1536

// offs[f] = 256 * {0,1,2,6,10,12}  -> packed nibbles 0x00CA6210
__device__ __forceinline__ int field_off(int f) {
    return (int)(((0xCA6210u >> (f * 4)) & 0xFu) << 8);
}

__device__ __forceinline__ double wave_reduce(double v) {
#pragma unroll
    for (int off = 32; off > 0; off >>= 1)
        v += __shfl_down(v, off, 64);
    return v;   // lane 0 holds the wave sum (fixed order)
}

__global__ __launch_bounds__(BLK)
void gan_loss_fused(const float* __restrict__ prob,
                    const int* __restrict__ target,
                    const float* __restrict__ reward,
                    double* __restrict__ partial,        // [NBLOCKS], ws+128
                    unsigned int* __restrict__ counter,  // ws+0, zeroed each call
                    float* __restrict__ out) {
    const int tid = threadIdx.x;
    const int gid = blockIdx.x * BLK + tid;
    const int n   = gid / NFLD;              // magic-mul, no HW div
    const int f   = gid - n * NFLD;

    const int col = field_off(f) + target[gid];
    double v = (double)prob[(size_t)n * NCOLS + col] * (double)reward[n];

    // block reduce: wave shuffle (fixed order) then 4 wave sums via LDS
    __shared__ double sm[BLK / 64];
    __shared__ bool isLast;
    v = wave_reduce(v);
    if ((tid & 63) == 0) sm[tid >> 6] = v;
    __syncthreads();

    if (tid == 0) {
        double bsum = ((sm[0] + sm[1]) + sm[2]) + sm[3];
        __hip_atomic_store(&partial[blockIdx.x], bsum,
                           __ATOMIC_RELEASE, __HIP_MEMORY_SCOPE_AGENT);
        unsigned int old = __hip_atomic_fetch_add(counter, 1u,
                           __ATOMIC_ACQ_REL, __HIP_MEMORY_SCOPE_AGENT);
        isLast = (old == NBLOCKS - 1);
    }
    __syncthreads();
    if (!isLast) return;

    // last block: fixed-order sum of all 1536 partials
    double s = 0.0;
#pragma unroll
    for (int i = 0; i < NBLOCKS / BLK; ++i)   // 6 per thread: tid, tid+256, ...
        s += __hip_atomic_load(&partial[tid + i * BLK],
                               __ATOMIC_RELAXED, __HIP_MEMORY_SCOPE_AGENT);
    s = wave_reduce(s);
    if ((tid & 63) == 0) sm[tid >> 6] = s;
    __syncthreads();
    if (tid == 0) {
        double tot = ((sm[0] + sm[1]) + sm[2]) + sm[3];
        out[0] = (float)(-tot / ((double)NROWS * (double)NFLD));
    }
}

extern "C" void kernel_launch(void* const* d_in, const int* in_sizes, int n_in,
                              void* d_out, int out_size, void* d_ws, size_t ws_size,
                              hipStream_t stream) {
    const float* prob   = (const float*)d_in[0];   // (64,1024,3200) f32
    const int*   target = (const int*)d_in[1];     // (65536,6) int32
    const float* reward = (const float*)d_in[2];   // (65536,) f32
    // d_in[3] = weights: unused by reference forward

    unsigned int* counter = (unsigned int*)d_ws;          // 4 B at ws+0
    double* partial = (double*)((char*)d_ws + 128);       // 1536 doubles
    float*  out     = (float*)d_out;

    hipMemsetAsync(counter, 0, sizeof(unsigned int), stream);  // graph-capturable
    gan_loss_fused<<<NBLOCKS, BLK, 0, stream>>>(prob, target, reward,
                                                partial, counter, out);
}

// Round 4
// 14.996 us; speedup vs baseline: 4.4199x; 4.4199x over previous
//
#include <hip/hip_runtime.h>

// GANLoss gather-reduce, two kernels, no atomics:
//   out = -(1/(N*F)) * sum_{n,f} prob_flat[n, OFF[f]+target[n,f]] * reward[n]
// N = 65536, C = 3200, F = 6.  target is int32 (harness convention).
// Kernel 1: one thread per (n,f) -> 1536 blocks x 256 (24 waves/CU), one
//           double partial per block (fixed-order shuffle+LDS reduce).
// Kernel 2: one block sums the 1536 partials in fixed order.
// R3 lesson: 1536 same-address device-scope atomics serialize (~+50us) —
// a tiny second launch is far cheaper than cross-XCD atomic coordination.

#define NROWS   65536
#define NCOLS   3200
#define NFLD    6
#define NTOT    (NROWS * NFLD)      // 393216
#define BLK     256
#define NBLOCKS (NTOT / BLK)        // 1536

// offs[f] = 256 * {0,1,2,6,10,12}  -> packed nibbles 0x00CA6210
__device__ __forceinline__ int field_off(int f) {
    return (int)(((0xCA6210u >> (f * 4)) & 0xFu) << 8);
}

__device__ __forceinline__ double wave_reduce(double v) {
#pragma unroll
    for (int off = 32; off > 0; off >>= 1)
        v += __shfl_down(v, off, 64);
    return v;   // lane 0 holds the wave sum (fixed order)
}

__global__ __launch_bounds__(BLK)
void gan_loss_gather(const float* __restrict__ prob,
                     const int* __restrict__ target,
                     const float* __restrict__ reward,
                     double* __restrict__ partial) {
    const int tid = threadIdx.x;
    const int gid = blockIdx.x * BLK + tid;
    const int n   = gid / NFLD;              // compiler magic-mul
    const int f   = gid - n * NFLD;

    const int col = field_off(f) + target[gid];
    double v = (double)prob[(size_t)n * NCOLS + col] * (double)reward[n];

    __shared__ double sm[BLK / 64];
    v = wave_reduce(v);
    if ((tid & 63) == 0) sm[tid >> 6] = v;
    __syncthreads();
    if (tid == 0)
        partial[blockIdx.x] = ((sm[0] + sm[1]) + sm[2]) + sm[3];
}

__global__ __launch_bounds__(BLK)
void gan_loss_final(const double* __restrict__ partial,
                    float* __restrict__ out) {
    const int tid = threadIdx.x;
    double s = 0.0;
#pragma unroll
    for (int i = 0; i < NBLOCKS / BLK; ++i)   // 6 per thread: tid, tid+256, ...
        s += partial[tid + i * BLK];

    __shared__ double sm[BLK / 64];
    s = wave_reduce(s);
    if ((tid & 63) == 0) sm[tid >> 6] = s;
    __syncthreads();
    if (tid == 0) {
        double tot = ((sm[0] + sm[1]) + sm[2]) + sm[3];
        out[0] = (float)(-tot / ((double)NROWS * (double)NFLD));
    }
}

extern "C" void kernel_launch(void* const* d_in, const int* in_sizes, int n_in,
                              void* d_out, int out_size, void* d_ws, size_t ws_size,
                              hipStream_t stream) {
    const float* prob   = (const float*)d_in[0];   // (64,1024,3200) f32
    const int*   target = (const int*)d_in[1];     // (65536,6) int32
    const float* reward = (const float*)d_in[2];   // (65536,) f32
    // d_in[3] = weights: unused by reference forward

    double* partial = (double*)d_ws;               // 1536 doubles = 12 KB
    float*  out     = (float*)d_out;

    gan_loss_gather<<<NBLOCKS, BLK, 0, stream>>>(prob, target, reward, partial);
    gan_loss_final<<<1, BLK, 0, stream>>>(partial, out);
}